// Round 1
// baseline (23251.994 us; speedup 1.0000x reference)
//
#include <hip/hip_runtime.h>
#include <math.h>

// Problem constants
#define B  64
#define T  512
#define I0 256
#define H  512
#define M  (B*T)          // 32768 rows

// Recurrence partitioning: 8 batch-groups x 32 col-chunks = 256 persistent WGs
#define NG 8              // batch groups (8 batches each)
#define BG 8              // batches per group
#define NC 32             // column chunks (16 cols each)
#define CC 16             // cols per chunk
#define HP (H+4)          // padded LDS stride (breaks bank aliasing, keeps 16B align)

// ---------------------------------------------------------------------------
// GEMM: C[M,N] = A[M,K] * W[N,K]^T   (fp32, 64x64 tile, BK=16, 256 threads)
// ---------------------------------------------------------------------------
template<int K>
__global__ __launch_bounds__(256)
void gemm_awt(const float* __restrict__ A, const float* __restrict__ W,
              float* __restrict__ C) {
  __shared__ float As[16][68];   // [k][m], padded
  __shared__ float Bs[16][68];   // [k][n]
  const int tid = threadIdx.x;
  const int tx = tid & 15, ty = tid >> 4;
  const int m0 = blockIdx.x * 64, n0 = blockIdx.y * 64;
  float acc[4][4] = {};
  for (int k0 = 0; k0 < K; k0 += 16) {
    // stage 64x16 tiles of A and W (float4 loads, transposed scatter to LDS)
    {
      int e = tid * 4;
      int m = e >> 4, k = e & 15;
      float4 v = *(const float4*)&A[(m0 + m) * K + k0 + k];
      As[k][m] = v.x; As[k+1][m] = v.y; As[k+2][m] = v.z; As[k+3][m] = v.w;
      float4 w = *(const float4*)&W[(n0 + m) * K + k0 + k];
      Bs[k][m] = w.x; Bs[k+1][m] = w.y; Bs[k+2][m] = w.z; Bs[k+3][m] = w.w;
    }
    __syncthreads();
    #pragma unroll
    for (int k = 0; k < 16; ++k) {
      float a[4], w[4];
      *(float4*)a = *(const float4*)&As[k][ty*4];
      *(float4*)w = *(const float4*)&Bs[k][tx*4];
      #pragma unroll
      for (int i = 0; i < 4; ++i)
        #pragma unroll
        for (int j = 0; j < 4; ++j)
          acc[i][j] += a[i] * w[j];
    }
    __syncthreads();
  }
  #pragma unroll
  for (int i = 0; i < 4; ++i) {
    float4 r;
    r.x = acc[i][0]; r.y = acc[i][1]; r.z = acc[i][2]; r.w = acc[i][3];
    *(float4*)&C[(m0 + ty*4 + i) * H + n0 + tx*4] = r;
  }
}

// ---------------------------------------------------------------------------
// Persistent recurrence: out[b,t,:] = tanh(xw[b*T+t,:] + out[b,t-1,:] @ Whh^T)
// One WG per (group g, chunk c). Whh rows [c*16, c*16+16) live in LDS for all
// 512 steps. Group-local sync via device-scope atomic flags (one per (g,t)).
// grid=256 blocks, LDS ~52KB -> all blocks resident (capacity 3/CU). Group g
// = blockIdx&7 so a group's 32 WGs share an XCD (dispatch round-robin heur.).
// ---------------------------------------------------------------------------
__global__ __launch_bounds__(256)
void rnn_rec(const float* __restrict__ xw,   // [M, H], row = b*T + t
             const float* __restrict__ Whh,  // [H, H]
             float* __restrict__ out,        // [B, T, H]
             int* __restrict__ flags)        // [NG * T], zeroed
{
  __shared__ float Ws[CC * HP];     // 33 KB: weight slice
  __shared__ float hs[BG * HP];     // 16.5 KB: h_{t-1} for this batch group
  __shared__ float red[4 * 8 * 18]; // cross-wave partial reduction
  __shared__ int s_dead;

  const int tid = threadIdx.x;
  const int g  = blockIdx.x & 7;
  const int cc = blockIdx.x >> 3;
  const int c0 = cc * CC;
  const int b0 = g * BG;
  int* gflags = flags + g * T;
  if (tid == 0) s_dead = 0;

  // load Whh slice once
  for (int idx = tid; idx < CC * (H/4); idx += 256) {
    int r  = idx >> 7;              // H/4 == 128
    int k4 = (idx & 127) << 2;
    float4 v = *(const float4*)&Whh[(c0 + r) * H + k4];
    *(float4*)&Ws[r * HP + k4] = v;
  }
  __syncthreads();

  // compute mapping: wave owns a K-quarter; lane = (b, col-pair)
  const int wv   = tid >> 6;
  const int lane = tid & 63;
  const int bb   = lane >> 3;       // 0..7
  const int c2   = lane & 7;        // col pair
  const float* w0p = &Ws[(2*c2)   * HP];
  const float* w1p = &Ws[(2*c2+1) * HP];
  const float* hp  = &hs[bb * HP];
  const int kbeg = wv * 128, kend = kbeg + 128;

  // reduction-phase mapping (threads 0..127 -> one output each)
  const int o  = tid & 127;
  const int bl = o >> 4, cl = o & 15;

  for (int t = 0; t < T; ++t) {
    if (t > 0) {
      if (tid == 0 && !s_dead) {
        long cnt = 0;
        while (__hip_atomic_load(gflags + (t-1), __ATOMIC_RELAXED,
                                 __HIP_MEMORY_SCOPE_AGENT) < NC) {
          __builtin_amdgcn_s_sleep(1);
          if (++cnt > 20000000L) { s_dead = 1; break; }  // safety valve
        }
      }
      __syncthreads();
      __threadfence();   // acquire: invalidate stale L1/L2 before reading h
      // stage h_{t-1} for this group's 8 batches
      for (int idx = tid; idx < BG * (H/4); idx += 256) {
        int r  = idx >> 7;
        int k4 = (idx & 127) << 2;
        float4 v = *(const float4*)&out[((b0 + r) * T + (t-1)) * H + k4];
        *(float4*)&hs[r * HP + k4] = v;
      }
    }
    float xwv = 0.f;
    if (tid < 128) xwv = xw[((b0 + bl) * T + t) * H + c0 + cl];
    __syncthreads();

    // partial dot over this wave's K-quarter
    float s0 = 0.f, s1 = 0.f;
    if (t > 0) {
      #pragma unroll 4
      for (int k = kbeg; k < kend; k += 4) {
        float4 hv = *(const float4*)&hp[k];
        float4 w0 = *(const float4*)&w0p[k];
        float4 w1 = *(const float4*)&w1p[k];
        s0 += w0.x*hv.x + w0.y*hv.y + w0.z*hv.z + w0.w*hv.w;
        s1 += w1.x*hv.x + w1.y*hv.y + w1.z*hv.z + w1.w*hv.w;
      }
    }
    red[(wv*8 + bb)*18 + 2*c2]     = s0;
    red[(wv*8 + bb)*18 + 2*c2 + 1] = s1;
    __syncthreads();

    if (tid < 128) {
      float sum = xwv;
      #pragma unroll
      for (int p = 0; p < 4; ++p) sum += red[(p*8 + bl)*18 + cl];
      out[((b0 + bl) * T + t) * H + c0 + cl] = tanhf(sum);
    }
    __syncthreads();             // all stores issued (barrier drains vmcnt)
    if (tid == 0) {
      __threadfence();           // release: flush to device scope
      atomicAdd(gflags + t, 1);
    }
  }
}

// ---------------------------------------------------------------------------
// ws layout: [0,64MB) xw (xw1 then reused for xw2) | [64MB,128MB) out1 |
//            [128MB, +32KB) flags (layer1 then layer2)
// required ws >= 128MB + 32KB
// ---------------------------------------------------------------------------
extern "C" void kernel_launch(void* const* d_in, const int* in_sizes, int n_in,
                              void* d_out, int out_size, void* d_ws, size_t ws_size,
                              hipStream_t stream) {
  const float* x    = (const float*)d_in[0];
  const float* Wih0 = (const float*)d_in[1];
  const float* Whh0 = (const float*)d_in[2];
  const float* Wih1 = (const float*)d_in[3];
  const float* Whh1 = (const float*)d_in[4];
  float* out = (float*)d_out;

  char* ws = (char*)d_ws;
  float* xw   = (float*)ws;                               // [M, H]
  float* out1 = (float*)(ws + (size_t)64*1024*1024);      // [B, T, H]
  int* flags1 = (int*)(ws + (size_t)128*1024*1024);       // [NG*T]
  int* flags2 = flags1 + NG*T;

  // flags must be zero every call (ws is re-poisoned before each timed launch)
  hipMemsetAsync(flags1, 0, 2 * NG * T * sizeof(int), stream);

  dim3 gg(M/64, H/64);
  // layer 1: input projection, then recurrence
  gemm_awt<I0><<<gg, 256, 0, stream>>>(x, Wih0, xw);
  rnn_rec<<<256, 256, 0, stream>>>(xw, Whh0, out1, flags1);
  // layer 2: input projection (reads out1), then recurrence -> d_out
  gemm_awt<H><<<gg, 256, 0, stream>>>(out1, Wih1, xw);
  rnn_rec<<<256, 256, 0, stream>>>(xw, Whh1, out, flags2);
}

// Round 2
// 7304.783 us; speedup vs baseline: 3.1831x; 3.1831x over previous
//
#include <hip/hip_runtime.h>
#include <math.h>

// Problem constants
#define B  64
#define T  512
#define I0 256
#define H  512
#define M  (B*T)          // 32768 rows

// Recurrence partitioning: 8 batch-groups x 32 col-chunks = 256 persistent WGs
#define NG 8              // batch groups (8 batches each)
#define BG 8              // batches per group
#define NC 32             // column chunks (16 cols each)
#define CC 16             // cols per chunk
#define HP (H+4)          // padded LDS stride

// ---------------------------------------------------------------------------
// GEMM: C[M,N] = A[M,K] * W[N,K]^T   (fp32, 64x64 tile, BK=16, 256 threads)
// ---------------------------------------------------------------------------
template<int K>
__global__ __launch_bounds__(256)
void gemm_awt(const float* __restrict__ A, const float* __restrict__ W,
              float* __restrict__ C) {
  __shared__ float As[16][68];   // [k][m], padded
  __shared__ float Bs[16][68];   // [k][n]
  const int tid = threadIdx.x;
  const int tx = tid & 15, ty = tid >> 4;
  const int m0 = blockIdx.x * 64, n0 = blockIdx.y * 64;
  float acc[4][4] = {};
  for (int k0 = 0; k0 < K; k0 += 16) {
    {
      int e = tid * 4;
      int m = e >> 4, k = e & 15;
      float4 v = *(const float4*)&A[(m0 + m) * K + k0 + k];
      As[k][m] = v.x; As[k+1][m] = v.y; As[k+2][m] = v.z; As[k+3][m] = v.w;
      float4 w = *(const float4*)&W[(n0 + m) * K + k0 + k];
      Bs[k][m] = w.x; Bs[k+1][m] = w.y; Bs[k+2][m] = w.z; Bs[k+3][m] = w.w;
    }
    __syncthreads();
    #pragma unroll
    for (int k = 0; k < 16; ++k) {
      float a[4], w[4];
      *(float4*)a = *(const float4*)&As[k][ty*4];
      *(float4*)w = *(const float4*)&Bs[k][tx*4];
      #pragma unroll
      for (int i = 0; i < 4; ++i)
        #pragma unroll
        for (int j = 0; j < 4; ++j)
          acc[i][j] += a[i] * w[j];
    }
    __syncthreads();
  }
  #pragma unroll
  for (int i = 0; i < 4; ++i) {
    float4 r;
    r.x = acc[i][0]; r.y = acc[i][1]; r.z = acc[i][2]; r.w = acc[i][3];
    *(float4*)&C[(m0 + ty*4 + i) * H + n0 + tx*4] = r;
  }
}

// ---------------------------------------------------------------------------
// Persistent recurrence. Cross-block h exchange goes through the coherence
// point (Infinity Cache) via relaxed AGENT-scope atomic loads/stores (sc0 sc1
// cache-bypass) — NO __threadfence / L2 writeback-invalidate anywhere.
// Ordering: __syncthreads drains vmcnt before tid0's flag atomicAdd; the
// consumer's barrier after the flag-wait orders the subsequent h loads.
// ---------------------------------------------------------------------------
__global__ __launch_bounds__(256)
void rnn_rec(const float* __restrict__ xw,   // [M, H], row = b*T + t
             const float* __restrict__ Whh,  // [H, H]
             float* __restrict__ out,        // [B, T, H]
             int* __restrict__ flags)        // [NG * T], zeroed
{
  __shared__ float Ws[CC * HP];     // 33 KB: weight slice (resident all steps)
  __shared__ float hs[BG * HP];     // 16.5 KB: h_{t-1} for this batch group
  __shared__ float red[4 * 8 * 18]; // cross-wave partial reduction
  __shared__ int s_dead;

  const int tid = threadIdx.x;
  const int g  = blockIdx.x & 7;
  const int cc = blockIdx.x >> 3;
  const int c0 = cc * CC;
  const int b0 = g * BG;
  int* gflags = flags + g * T;
  if (tid == 0) s_dead = 0;

  // load Whh slice once (cached loads — weights are read-only)
  for (int idx = tid; idx < CC * (H/4); idx += 256) {
    int r  = idx >> 7;              // H/4 == 128
    int k4 = (idx & 127) << 2;
    float4 v = *(const float4*)&Whh[(c0 + r) * H + k4];
    *(float4*)&Ws[r * HP + k4] = v;
  }
  __syncthreads();

  // compute mapping: wave owns a K-quarter; lane = (b, col-pair)
  const int wv   = tid >> 6;
  const int lane = tid & 63;
  const int bb   = lane >> 3;       // 0..7
  const int c2   = lane & 7;        // col pair
  const float* w0p = &Ws[(2*c2)   * HP];
  const float* w1p = &Ws[(2*c2+1) * HP];
  const float* hp  = &hs[bb * HP];
  const int kbeg = wv * 128, kend = kbeg + 128;

  // reduction-phase mapping (threads 0..127 -> one output each)
  const int o  = tid & 127;
  const int bl = o >> 4, cl = o & 15;

  for (int t = 0; t < T; ++t) {
    if (t > 0) {
      if (tid == 0 && !s_dead) {
        long cnt = 0;
        while (__hip_atomic_load(gflags + (t-1), __ATOMIC_RELAXED,
                                 __HIP_MEMORY_SCOPE_AGENT) < NC) {
          __builtin_amdgcn_s_sleep(1);
          if (++cnt > 1000000L) { s_dead = 1; break; }  // safety valve
        }
      }
      __syncthreads();
      // stage h_{t-1}: cache-bypassing loads straight from the coherence point
      for (int i = tid; i < BG * H; i += 256) {
        int r = i >> 9, k = i & 511;
        hs[r * HP + k] = __hip_atomic_load(
            &out[((b0 + r) * T + (t-1)) * H + k],
            __ATOMIC_RELAXED, __HIP_MEMORY_SCOPE_AGENT);
      }
    }
    float xwv = 0.f;
    if (tid < 128) xwv = xw[((b0 + bl) * T + t) * H + c0 + cl];
    __syncthreads();

    // partial dot over this wave's K-quarter
    float s0 = 0.f, s1 = 0.f;
    if (t > 0) {
      #pragma unroll 4
      for (int k = kbeg; k < kend; k += 4) {
        float4 hv = *(const float4*)&hp[k];
        float4 w0 = *(const float4*)&w0p[k];
        float4 w1 = *(const float4*)&w1p[k];
        s0 += w0.x*hv.x + w0.y*hv.y + w0.z*hv.z + w0.w*hv.w;
        s1 += w1.x*hv.x + w1.y*hv.y + w1.z*hv.z + w1.w*hv.w;
      }
    }
    red[(wv*8 + bb)*18 + 2*c2]     = s0;
    red[(wv*8 + bb)*18 + 2*c2 + 1] = s1;
    __syncthreads();

    if (tid < 128) {
      float sum = xwv;
      #pragma unroll
      for (int p = 0; p < 4; ++p) sum += red[(p*8 + bl)*18 + cl];
      // write-through store: lands at the coherence point, no flush needed
      __hip_atomic_store(&out[((b0 + bl) * T + t) * H + c0 + cl], tanhf(sum),
                         __ATOMIC_RELAXED, __HIP_MEMORY_SCOPE_AGENT);
    }
    __syncthreads();             // drains vmcnt -> all h stores complete
    if (tid == 0) {
      atomicAdd(gflags + t, 1); // device-scope, memory-side: safe without fence
    }
  }
}

// ---------------------------------------------------------------------------
// ws layout: [0,64MB) xw | [64MB,128MB) out1 | [128MB,+32KB) flags
// ---------------------------------------------------------------------------
extern "C" void kernel_launch(void* const* d_in, const int* in_sizes, int n_in,
                              void* d_out, int out_size, void* d_ws, size_t ws_size,
                              hipStream_t stream) {
  const float* x    = (const float*)d_in[0];
  const float* Wih0 = (const float*)d_in[1];
  const float* Whh0 = (const float*)d_in[2];
  const float* Wih1 = (const float*)d_in[3];
  const float* Whh1 = (const float*)d_in[4];
  float* out = (float*)d_out;

  char* ws = (char*)d_ws;
  float* xw   = (float*)ws;                               // [M, H]
  float* out1 = (float*)(ws + (size_t)64*1024*1024);      // [B, T, H]
  int* flags1 = (int*)(ws + (size_t)128*1024*1024);       // [NG*T]
  int* flags2 = flags1 + NG*T;

  hipMemsetAsync(flags1, 0, 2 * NG * T * sizeof(int), stream);

  dim3 gg(M/64, H/64);
  gemm_awt<I0><<<gg, 256, 0, stream>>>(x, Wih0, xw);
  rnn_rec<<<256, 256, 0, stream>>>(xw, Whh0, out1, flags1);
  gemm_awt<H><<<gg, 256, 0, stream>>>(out1, Wih1, xw);
  rnn_rec<<<256, 256, 0, stream>>>(xw, Whh1, out, flags2);
}

// Round 3
// 3718.092 us; speedup vs baseline: 6.2537x; 1.9647x over previous
//
#include <hip/hip_runtime.h>
#include <math.h>

#define B   64
#define T   512
#define I0  256
#define H   512
#define M   (B*T)

#define NGR 4        // batch groups (16 batches each -> MFMA M=16)
#define BGR 16
#define NCH 16       // col chunks
#define CCH 32       // cols per chunk = 2 MFMA tiles
#define HS_STRIDE 520  // staged-h row stride in ushorts (512+8 -> 2-way-free banks)

typedef __attribute__((ext_vector_type(8))) short short8;
typedef __attribute__((ext_vector_type(4))) float floatx4;

static __device__ __forceinline__ unsigned short f2bf(float f) {
  unsigned u = __float_as_uint(f);
  u += 0x7fff + ((u >> 16) & 1);          // RNE
  return (unsigned short)(u >> 16);
}

// ---------------------------------------------------------------------------
// fp32 GEMM for layer-1 input projection: xw[M,H] = x[M,I0] * Wih0[H,I0]^T
// ---------------------------------------------------------------------------
template<int K>
__global__ __launch_bounds__(256)
void gemm_awt(const float* __restrict__ A, const float* __restrict__ W,
              float* __restrict__ C) {
  __shared__ float As[16][68];
  __shared__ float Bs[16][68];
  const int tid = threadIdx.x;
  const int tx = tid & 15, ty = tid >> 4;
  const int m0 = blockIdx.x * 64, n0 = blockIdx.y * 64;
  float acc[4][4] = {};
  for (int k0 = 0; k0 < K; k0 += 16) {
    {
      int e = tid * 4;
      int m = e >> 4, k = e & 15;
      float4 v = *(const float4*)&A[(m0 + m) * K + k0 + k];
      As[k][m] = v.x; As[k+1][m] = v.y; As[k+2][m] = v.z; As[k+3][m] = v.w;
      float4 w = *(const float4*)&W[(n0 + m) * K + k0 + k];
      Bs[k][m] = w.x; Bs[k+1][m] = w.y; Bs[k+2][m] = w.z; Bs[k+3][m] = w.w;
    }
    __syncthreads();
    #pragma unroll
    for (int k = 0; k < 16; ++k) {
      float a[4], w[4];
      *(float4*)a = *(const float4*)&As[k][ty*4];
      *(float4*)w = *(const float4*)&Bs[k][tx*4];
      #pragma unroll
      for (int i = 0; i < 4; ++i)
        #pragma unroll
        for (int j = 0; j < 4; ++j)
          acc[i][j] += a[i] * w[j];
    }
    __syncthreads();
  }
  #pragma unroll
  for (int i = 0; i < 4; ++i) {
    float4 r;
    r.x = acc[i][0]; r.y = acc[i][1]; r.z = acc[i][2]; r.w = acc[i][3];
    *(float4*)&C[(m0 + ty*4 + i) * H + n0 + tx*4] = r;
  }
}

// ---------------------------------------------------------------------------
// Pack a [H,H] fp32 weight (out-col major, i.e. out = h @ W^T) into bf16
// B-fragment lane order: dst[c][tau][i][lane][j] = bf16(W[c*32+tau*16+(lane&15)]
//                                                       [i*32+(lane>>4)*8+j])
// ---------------------------------------------------------------------------
__global__ __launch_bounds__(256)
void pack_w(const float* __restrict__ W, unsigned short* __restrict__ dst) {
  int idx = blockIdx.x * 256 + threadIdx.x;   // over 16*2*16*64 = 32768
  int l = idx & 63, i = (idx >> 6) & 15, tau = (idx >> 10) & 1, c = idx >> 11;
  int col = c * CCH + tau * 16 + (l & 15);
  int k0  = i * 32 + (l >> 4) * 8;
  const float* src = &W[col * H + k0];
  unsigned v[4];
  #pragma unroll
  for (int j = 0; j < 4; ++j) {
    unsigned lo = f2bf(src[2*j]);
    unsigned hi = f2bf(src[2*j + 1]);
    v[j] = lo | (hi << 16);
  }
  *(uint4*)&dst[(size_t)idx * 8] = make_uint4(v[0], v[1], v[2], v[3]);
}

// ---------------------------------------------------------------------------
// Fused 2-layer pipelined persistent recurrence. 64 blocks = 4 groups x 16
// chunks. Round r: waves 0-1 compute h0_r (layer 1), waves 2-3 compute
// h1_{r-1} (layer 2, incl. its input projection from the SAME staged h0).
// h exchanged as bf16 via depth-2 rings with IC-coherent relaxed atomics.
// ---------------------------------------------------------------------------
__global__ __launch_bounds__(256)
void rnn_fused(const float* __restrict__ xw,
               const unsigned short* __restrict__ wp0,  // Whh0 packed
               const unsigned short* __restrict__ wp1,  // Wih1 packed
               const unsigned short* __restrict__ wp2,  // Whh1 packed
               unsigned short* __restrict__ ring0,      // [2][B][H] bf16
               unsigned short* __restrict__ ring1,      // [2][B][H] bf16
               float* __restrict__ dout,                // [B][T][H]
               int* __restrict__ flag0,                 // [NGR][T]
               int* __restrict__ flag1)                 // [NGR][T]
{
  extern __shared__ unsigned short smem[];
  unsigned short* Ws0 = smem;             // [2][16][64][8] = 16384 us
  unsigned short* Wi1 = Ws0 + 16384;
  unsigned short* Ws1 = Wi1 + 16384;
  unsigned short* hs0 = Ws1 + 16384;      // [16][HS_STRIDE] = 8320 us
  unsigned short* hs1 = hs0 + 8320;

  const int tid   = threadIdx.x;
  const int g     = blockIdx.x & 3;
  const int chunk = blockIdx.x >> 2;
  const int c0    = chunk * CCH;
  const int b0    = g * BGR;
  const int wv    = tid >> 6;
  const int lane  = tid & 63;
  const int mrow  = lane & 15;
  const int quad  = lane >> 4;

  // stage packed weight slices (cached reads; written by pack_w earlier)
  {
    const uint4* s0 = (const uint4*)(wp0 + (size_t)chunk * 16384);
    const uint4* s1 = (const uint4*)(wp1 + (size_t)chunk * 16384);
    const uint4* s2 = (const uint4*)(wp2 + (size_t)chunk * 16384);
    uint4* d0 = (uint4*)Ws0; uint4* d1 = (uint4*)Wi1; uint4* d2 = (uint4*)Ws1;
    for (int i = tid; i < 2048; i += 256) { d0[i] = s0[i]; d1[i] = s1[i]; d2[i] = s2[i]; }
  }
  // zero hs1 (read by layer-2 MFMA at r==1 before first staging)
  for (int i = tid; i < 2080; i += 256) ((unsigned long long*)hs1)[i] = 0ULL;
  __syncthreads();

  int dead0 = 0, dead1 = 0;
  int* f0g = flag0 + g * T;
  int* f1g = flag1 + g * T;

  for (int r = 0; r <= T; ++r) {
    // ---- wait for producers (two pollers in different waves, overlap) ----
    if (r >= 1 && tid == 0 && !dead0) {
      long cnt = 0;
      while (__hip_atomic_load(f0g + (r-1), __ATOMIC_RELAXED,
                               __HIP_MEMORY_SCOPE_AGENT) < NCH) {
        __builtin_amdgcn_s_sleep(1);
        if (++cnt > 1000000L) { dead0 = 1; break; }
      }
    }
    if (r >= 2 && tid == 64 && !dead1) {
      long cnt = 0;
      while (__hip_atomic_load(f1g + (r-2), __ATOMIC_RELAXED,
                               __HIP_MEMORY_SCOPE_AGENT) < NCH) {
        __builtin_amdgcn_s_sleep(1);
        if (++cnt > 1000000L) { dead1 = 1; break; }
      }
    }
    __syncthreads();

    // ---- stage h rows (uncached 8B atomic loads from coherence point) ----
    if (r >= 1) {
      const unsigned long long* src =
          (const unsigned long long*)(ring0 + (size_t)((r-1) & 1) * B * H);
      for (int ii = tid; ii < 2048; ii += 256) {
        int row = ii >> 7, c8 = ii & 127;
        unsigned long long v = __hip_atomic_load(src + (b0 + row) * 128 + c8,
            __ATOMIC_RELAXED, __HIP_MEMORY_SCOPE_AGENT);
        *(unsigned long long*)&hs0[row * HS_STRIDE + c8 * 4] = v;
      }
    }
    if (r >= 2) {
      const unsigned long long* src =
          (const unsigned long long*)(ring1 + (size_t)((r-2) & 1) * B * H);
      for (int ii = tid; ii < 2048; ii += 256) {
        int row = ii >> 7, c8 = ii & 127;
        unsigned long long v = __hip_atomic_load(src + (b0 + row) * 128 + c8,
            __ATOMIC_RELAXED, __HIP_MEMORY_SCOPE_AGENT);
        *(unsigned long long*)&hs1[row * HS_STRIDE + c8 * 4] = v;
      }
    }
    __syncthreads();

    // ---- compute ----
    if (wv < 2) {                       // layer 1, tile wv
      if (r < T) {
        floatx4 acc = {0.f, 0.f, 0.f, 0.f};
        if (r >= 1) {
          const unsigned short* wb = Ws0 + wv * 8192;
          const unsigned short* ha = hs0 + mrow * HS_STRIDE + quad * 8;
          #pragma unroll
          for (int i = 0; i < 16; ++i) {
            short8 a = *(const short8*)(ha + i * 32);
            short8 b = *(const short8*)(wb + (i * 64 + lane) * 8);
            acc = __builtin_amdgcn_mfma_f32_16x16x32_bf16(a, b, acc, 0, 0, 0);
          }
        }
        const int ccol = c0 + wv * 16 + mrow;
        unsigned short* rdst = ring0 + (size_t)(r & 1) * B * H;
        #pragma unroll
        for (int i = 0; i < 4; ++i) {
          int b = b0 + quad * 4 + i;
          float v = acc[i] + xw[((size_t)b * T + r) * H + ccol];
          float h = tanhf(v);
          __hip_atomic_store(rdst + (size_t)b * H + ccol, f2bf(h),
                             __ATOMIC_RELAXED, __HIP_MEMORY_SCOPE_AGENT);
        }
      }
    } else {                            // layer 2, tile wv-2, step t2 = r-1
      if (r >= 1) {
        floatx4 acc = {0.f, 0.f, 0.f, 0.f};
        const int tt = wv - 2;
        const unsigned short* wi  = Wi1 + tt * 8192;
        const unsigned short* wh  = Ws1 + tt * 8192;
        const unsigned short* ha0 = hs0 + mrow * HS_STRIDE + quad * 8;
        const unsigned short* ha1 = hs1 + mrow * HS_STRIDE + quad * 8;
        #pragma unroll
        for (int i = 0; i < 16; ++i) {
          short8 a = *(const short8*)(ha0 + i * 32);
          short8 b = *(const short8*)(wi + (i * 64 + lane) * 8);
          acc = __builtin_amdgcn_mfma_f32_16x16x32_bf16(a, b, acc, 0, 0, 0);
        }
        #pragma unroll
        for (int i = 0; i < 16; ++i) {
          short8 a = *(const short8*)(ha1 + i * 32);
          short8 b = *(const short8*)(wh + (i * 64 + lane) * 8);
          acc = __builtin_amdgcn_mfma_f32_16x16x32_bf16(a, b, acc, 0, 0, 0);
        }
        const int ccol = c0 + tt * 16 + mrow;
        const int t2 = r - 1;
        unsigned short* rdst = ring1 + (size_t)(t2 & 1) * B * H;
        #pragma unroll
        for (int i = 0; i < 4; ++i) {
          int b = b0 + quad * 4 + i;
          float h = tanhf(acc[i]);
          __hip_atomic_store(&dout[((size_t)b * T + t2) * H + ccol], h,
                             __ATOMIC_RELAXED, __HIP_MEMORY_SCOPE_AGENT);
          __hip_atomic_store(rdst + (size_t)b * H + ccol, f2bf(h),
                             __ATOMIC_RELAXED, __HIP_MEMORY_SCOPE_AGENT);
        }
      }
    }
    __syncthreads();                    // drain h stores (vmcnt) before flags
    if (tid == 0 && r < T) atomicAdd(f0g + r, 1);
    if (tid == 64 && r >= 1) atomicAdd(f1g + (r - 1), 1);
  }
}

#define SMEM_BYTES ((3 * 16384 + 2 * 8320) * 2)   // 131584

// ---------------------------------------------------------------------------
// ws: [0,64MB) xw | +0/512KB/1MB packed W x3 | +1.5MB ring0 | +1.625MB ring1 |
//     +1.75MB flags (2 x 8KB)
// ---------------------------------------------------------------------------
extern "C" void kernel_launch(void* const* d_in, const int* in_sizes, int n_in,
                              void* d_out, int out_size, void* d_ws, size_t ws_size,
                              hipStream_t stream) {
  const float* x    = (const float*)d_in[0];
  const float* Wih0 = (const float*)d_in[1];
  const float* Whh0 = (const float*)d_in[2];
  const float* Wih1 = (const float*)d_in[3];
  const float* Whh1 = (const float*)d_in[4];
  float* out = (float*)d_out;

  char* ws = (char*)d_ws;
  float* xw = (float*)ws;
  unsigned short* wp0 = (unsigned short*)(ws + (size_t)64*1024*1024);
  unsigned short* wp1 = (unsigned short*)(ws + (size_t)64*1024*1024 + 512*1024);
  unsigned short* wp2 = (unsigned short*)(ws + (size_t)64*1024*1024 + 1024*1024);
  unsigned short* ring0 = (unsigned short*)(ws + (size_t)64*1024*1024 + 1536*1024);
  unsigned short* ring1 = (unsigned short*)(ws + (size_t)64*1024*1024 + 1664*1024);
  int* flag0 = (int*)(ws + (size_t)64*1024*1024 + 1792*1024);
  int* flag1 = flag0 + NGR * T;

  hipMemsetAsync(flag0, 0, 2 * NGR * T * sizeof(int), stream);
  hipFuncSetAttribute((const void*)rnn_fused,
                      hipFuncAttributeMaxDynamicSharedMemorySize, SMEM_BYTES);

  pack_w<<<128, 256, 0, stream>>>(Whh0, wp0);
  pack_w<<<128, 256, 0, stream>>>(Wih1, wp1);
  pack_w<<<128, 256, 0, stream>>>(Whh1, wp2);

  dim3 gg(M/64, H/64);
  gemm_awt<I0><<<gg, 256, 0, stream>>>(x, Wih0, xw);

  rnn_fused<<<NGR * NCH, 256, SMEM_BYTES, stream>>>(
      xw, wp0, wp1, wp2, ring0, ring1, out, flag0, flag1);
}

// Round 4
// 1569.169 us; speedup vs baseline: 14.8180x; 2.3695x over previous
//
#include <hip/hip_runtime.h>
#include <math.h>

#define B   64
#define T   512
#define I0  256
#define H   512
#define M   (B*T)

#define NGR 4        // batch groups (16 batches each -> MFMA M=16)
#define BGR 16
#define NCH 16       // col chunks
#define CCH 32       // cols per chunk = 2 MFMA tiles
#define HS_STRIDE 520  // staged-h row stride in ushorts

typedef __attribute__((ext_vector_type(8))) short short8;
typedef __attribute__((ext_vector_type(4))) float floatx4;

static __device__ __forceinline__ unsigned short f2bf(float f) {
  unsigned u = __float_as_uint(f);
  u += 0x7fff + ((u >> 16) & 1);          // RNE
  return (unsigned short)(u >> 16);
}

// ---------------------------------------------------------------------------
// fp32 GEMM for layer-1 input projection: xw[M,H] = x[M,I0] * Wih0[H,I0]^T
// ---------------------------------------------------------------------------
template<int K>
__global__ __launch_bounds__(256)
void gemm_awt(const float* __restrict__ A, const float* __restrict__ W,
              float* __restrict__ C) {
  __shared__ float As[16][68];
  __shared__ float Bs[16][68];
  const int tid = threadIdx.x;
  const int tx = tid & 15, ty = tid >> 4;
  const int m0 = blockIdx.x * 64, n0 = blockIdx.y * 64;
  float acc[4][4] = {};
  for (int k0 = 0; k0 < K; k0 += 16) {
    {
      int e = tid * 4;
      int m = e >> 4, k = e & 15;
      float4 v = *(const float4*)&A[(m0 + m) * K + k0 + k];
      As[k][m] = v.x; As[k+1][m] = v.y; As[k+2][m] = v.z; As[k+3][m] = v.w;
      float4 w = *(const float4*)&W[(n0 + m) * K + k0 + k];
      Bs[k][m] = w.x; Bs[k+1][m] = w.y; Bs[k+2][m] = w.z; Bs[k+3][m] = w.w;
    }
    __syncthreads();
    #pragma unroll
    for (int k = 0; k < 16; ++k) {
      float a[4], w[4];
      *(float4*)a = *(const float4*)&As[k][ty*4];
      *(float4*)w = *(const float4*)&Bs[k][tx*4];
      #pragma unroll
      for (int i = 0; i < 4; ++i)
        #pragma unroll
        for (int j = 0; j < 4; ++j)
          acc[i][j] += a[i] * w[j];
    }
    __syncthreads();
  }
  #pragma unroll
  for (int i = 0; i < 4; ++i) {
    float4 r;
    r.x = acc[i][0]; r.y = acc[i][1]; r.z = acc[i][2]; r.w = acc[i][3];
    *(float4*)&C[(m0 + ty*4 + i) * H + n0 + tx*4] = r;
  }
}

// ---------------------------------------------------------------------------
// Pack [H,H] fp32 weight into bf16 B-fragment lane order.
// ---------------------------------------------------------------------------
__global__ __launch_bounds__(256)
void pack_w(const float* __restrict__ W, unsigned short* __restrict__ dst) {
  int idx = blockIdx.x * 256 + threadIdx.x;   // over 16*2*16*64 = 32768
  int l = idx & 63, i = (idx >> 6) & 15, tau = (idx >> 10) & 1, c = idx >> 11;
  int col = c * CCH + tau * 16 + (l & 15);
  int k0  = i * 32 + (l >> 4) * 8;
  const float* src = &W[col * H + k0];
  unsigned v[4];
  #pragma unroll
  for (int j = 0; j < 4; ++j) {
    unsigned lo = f2bf(src[2*j]);
    unsigned hi = f2bf(src[2*j + 1]);
    v[j] = lo | (hi << 16);
  }
  *(uint4*)&dst[(size_t)idx * 8] = make_uint4(v[0], v[1], v[2], v[3]);
}

// ---------------------------------------------------------------------------
// Fused 2-layer pipelined persistent recurrence. 64 blocks = 4 groups x 16
// chunks. Round r: waves 0-1 do layer-1 step r, waves 2-3 do layer-2 step
// r-1. Exchange rings read with BATCHED relaxed atomic loads (all 16 in
// flight before one waitcnt — the round-3 rolled loop serialized 16 IC
// round trips). All threads poll the flags (no poller->barrier hop).
// ---------------------------------------------------------------------------
__global__ __launch_bounds__(256)
void rnn_fused(const float* __restrict__ xw,
               const unsigned short* __restrict__ wp0,  // Whh0 packed
               const unsigned short* __restrict__ wp1,  // Wih1 packed
               const unsigned short* __restrict__ wp2,  // Whh1 packed
               unsigned short* __restrict__ ring0,      // [2][B][H] bf16
               unsigned short* __restrict__ ring1,      // [2][B][H] bf16
               float* __restrict__ dout,                // [B][T][H]
               int* __restrict__ flag0,                 // [NGR][T]
               int* __restrict__ flag1)                 // [NGR][T]
{
  extern __shared__ unsigned short smem[];
  unsigned short* Ws0 = smem;             // [2][16][64][8] = 16384 us
  unsigned short* Wi1 = Ws0 + 16384;
  unsigned short* Ws1 = Wi1 + 16384;
  unsigned short* hs0 = Ws1 + 16384;      // [16][HS_STRIDE]
  unsigned short* hs1 = hs0 + 8320;

  const int tid   = threadIdx.x;
  const int g     = blockIdx.x & 3;
  const int chunk = blockIdx.x >> 2;
  const int c0    = chunk * CCH;
  const int b0    = g * BGR;
  const int wv    = tid >> 6;
  const int lane  = tid & 63;
  const int mrow  = lane & 15;
  const int quad  = lane >> 4;

  // stage packed weight slices
  {
    const uint4* s0 = (const uint4*)(wp0 + (size_t)chunk * 16384);
    const uint4* s1 = (const uint4*)(wp1 + (size_t)chunk * 16384);
    const uint4* s2 = (const uint4*)(wp2 + (size_t)chunk * 16384);
    uint4* d0 = (uint4*)Ws0; uint4* d1 = (uint4*)Wi1; uint4* d2 = (uint4*)Ws1;
    for (int i = tid; i < 2048; i += 256) { d0[i] = s0[i]; d1[i] = s1[i]; d2[i] = s2[i]; }
  }
  // zero hs1 (read by layer-2 MFMA at r==1 before first staging)
  for (int i = tid; i < 2080; i += 256) ((unsigned long long*)hs1)[i] = 0ULL;
  __syncthreads();

  int dead = 0;
  int* f0g = flag0 + g * T;
  int* f1g = flag1 + g * T;

  for (int r = 0; r <= T; ++r) {
    // ---- xw prefetch: independent of flags, overlap its latency with poll
    float xv[4];
    if (wv < 2 && r < T) {
      const int ccol = c0 + wv * 16 + mrow;
      #pragma unroll
      for (int i = 0; i < 4; ++i)
        xv[i] = xw[((size_t)(b0 + quad * 4 + i) * T + r) * H + ccol];
    }

    // ---- all threads poll producers' flags (wave-coalesced same-addr loads)
    if (r >= 1 && !dead) {
      const int need1 = (r >= 2);
      long cnt = 0;
      for (;;) {
        int a = __hip_atomic_load(f0g + (r-1), __ATOMIC_RELAXED,
                                  __HIP_MEMORY_SCOPE_AGENT);
        int b = need1 ? __hip_atomic_load(f1g + (r-2), __ATOMIC_RELAXED,
                                          __HIP_MEMORY_SCOPE_AGENT) : NCH;
        if (a >= NCH && b >= NCH) break;
        __builtin_amdgcn_s_sleep(1);
        if (++cnt > 2000000L) { dead = 1; break; }
      }
    }

    // ---- stage h rows: ALL loads issued into regs first, then LDS writes
    unsigned long long v0[8], v1[8];
    if (r >= 1) {
      const unsigned long long* s0 =
          (const unsigned long long*)(ring0 + (size_t)((r-1) & 1) * B * H) + b0 * 128;
      #pragma unroll
      for (int j = 0; j < 8; ++j)
        v0[j] = __hip_atomic_load(s0 + j * 256 + tid,
                                  __ATOMIC_RELAXED, __HIP_MEMORY_SCOPE_AGENT);
    }
    if (r >= 2) {
      const unsigned long long* s1 =
          (const unsigned long long*)(ring1 + (size_t)((r-2) & 1) * B * H) + b0 * 128;
      #pragma unroll
      for (int j = 0; j < 8; ++j)
        v1[j] = __hip_atomic_load(s1 + j * 256 + tid,
                                  __ATOMIC_RELAXED, __HIP_MEMORY_SCOPE_AGENT);
    }
    if (r >= 1) {
      #pragma unroll
      for (int j = 0; j < 8; ++j) {
        int ii = j * 256 + tid, row = ii >> 7, c8 = ii & 127;
        *(unsigned long long*)&hs0[row * HS_STRIDE + c8 * 4] = v0[j];
      }
    }
    if (r >= 2) {
      #pragma unroll
      for (int j = 0; j < 8; ++j) {
        int ii = j * 256 + tid, row = ii >> 7, c8 = ii & 127;
        *(unsigned long long*)&hs1[row * HS_STRIDE + c8 * 4] = v1[j];
      }
    }
    __syncthreads();

    // ---- compute ----
    if (wv < 2) {                       // layer 1, tile wv
      if (r < T) {
        floatx4 acc = {0.f, 0.f, 0.f, 0.f};
        if (r >= 1) {
          const unsigned short* wb = Ws0 + wv * 8192;
          const unsigned short* ha = hs0 + mrow * HS_STRIDE + quad * 8;
          #pragma unroll
          for (int i = 0; i < 16; ++i) {
            short8 a = *(const short8*)(ha + i * 32);
            short8 b = *(const short8*)(wb + (i * 64 + lane) * 8);
            acc = __builtin_amdgcn_mfma_f32_16x16x32_bf16(a, b, acc, 0, 0, 0);
          }
        }
        const int ccol = c0 + wv * 16 + mrow;
        unsigned short* rdst = ring0 + (size_t)(r & 1) * B * H;
        #pragma unroll
        for (int i = 0; i < 4; ++i) {
          int b = b0 + quad * 4 + i;
          float h = tanhf(acc[i] + xv[i]);
          __hip_atomic_store(rdst + (size_t)b * H + ccol, f2bf(h),
                             __ATOMIC_RELAXED, __HIP_MEMORY_SCOPE_AGENT);
        }
      }
    } else {                            // layer 2, tile wv-2, step t2 = r-1
      if (r >= 1) {
        floatx4 acc = {0.f, 0.f, 0.f, 0.f};
        const int tt = wv - 2;
        const unsigned short* wi  = Wi1 + tt * 8192;
        const unsigned short* wh  = Ws1 + tt * 8192;
        const unsigned short* ha0 = hs0 + mrow * HS_STRIDE + quad * 8;
        const unsigned short* ha1 = hs1 + mrow * HS_STRIDE + quad * 8;
        #pragma unroll
        for (int i = 0; i < 16; ++i) {
          short8 a = *(const short8*)(ha0 + i * 32);
          short8 b = *(const short8*)(wi + (i * 64 + lane) * 8);
          acc = __builtin_amdgcn_mfma_f32_16x16x32_bf16(a, b, acc, 0, 0, 0);
        }
        #pragma unroll
        for (int i = 0; i < 16; ++i) {
          short8 a = *(const short8*)(ha1 + i * 32);
          short8 b = *(const short8*)(wh + (i * 64 + lane) * 8);
          acc = __builtin_amdgcn_mfma_f32_16x16x32_bf16(a, b, acc, 0, 0, 0);
        }
        const int ccol = c0 + tt * 16 + mrow;
        const int t2 = r - 1;
        unsigned short* rdst = ring1 + (size_t)(t2 & 1) * B * H;
        #pragma unroll
        for (int i = 0; i < 4; ++i) {
          int b = b0 + quad * 4 + i;
          float h = tanhf(acc[i]);
          dout[((size_t)b * T + t2) * H + ccol] = h;   // plain cached store
          __hip_atomic_store(rdst + (size_t)b * H + ccol, f2bf(h),
                             __ATOMIC_RELAXED, __HIP_MEMORY_SCOPE_AGENT);
        }
      }
    }
    __syncthreads();                    // drains vmcnt -> ring stores done
    if (tid == 0 && r < T) atomicAdd(f0g + r, 1);
    if (tid == 64 && r >= 1) atomicAdd(f1g + (r - 1), 1);
  }
}

#define SMEM_BYTES ((3 * 16384 + 2 * 8320) * 2)   // 131584

extern "C" void kernel_launch(void* const* d_in, const int* in_sizes, int n_in,
                              void* d_out, int out_size, void* d_ws, size_t ws_size,
                              hipStream_t stream) {
  const float* x    = (const float*)d_in[0];
  const float* Wih0 = (const float*)d_in[1];
  const float* Whh0 = (const float*)d_in[2];
  const float* Wih1 = (const float*)d_in[3];
  const float* Whh1 = (const float*)d_in[4];
  float* out = (float*)d_out;

  char* ws = (char*)d_ws;
  float* xw = (float*)ws;
  unsigned short* wp0 = (unsigned short*)(ws + (size_t)64*1024*1024);
  unsigned short* wp1 = (unsigned short*)(ws + (size_t)64*1024*1024 + 512*1024);
  unsigned short* wp2 = (unsigned short*)(ws + (size_t)64*1024*1024 + 1024*1024);
  unsigned short* ring0 = (unsigned short*)(ws + (size_t)64*1024*1024 + 1536*1024);
  unsigned short* ring1 = (unsigned short*)(ws + (size_t)64*1024*1024 + 1664*1024);
  int* flag0 = (int*)(ws + (size_t)64*1024*1024 + 1792*1024);
  int* flag1 = flag0 + NGR * T;

  hipMemsetAsync(flag0, 0, 2 * NGR * T * sizeof(int), stream);
  hipFuncSetAttribute((const void*)rnn_fused,
                      hipFuncAttributeMaxDynamicSharedMemorySize, SMEM_BYTES);

  pack_w<<<128, 256, 0, stream>>>(Whh0, wp0);
  pack_w<<<128, 256, 0, stream>>>(Wih1, wp1);
  pack_w<<<128, 256, 0, stream>>>(Whh1, wp2);

  dim3 gg(M/64, H/64);
  gemm_awt<I0><<<gg, 256, 0, stream>>>(x, Wih0, xw);

  rnn_fused<<<NGR * NCH, 256, SMEM_BYTES, stream>>>(
      xw, wp0, wp1, wp2, ring0, ring1, out, flag0, flag1);
}